// Round 4
// baseline (130.169 us; speedup 1.0000x reference)
//
#include <hip/hip_runtime.h>
#include <math.h>

#define SS 8
#define NN 4096
#define MM 64
#define LBOX 20.0f

typedef __attribute__((ext_vector_type(8)))  short    short8;
typedef __attribute__((ext_vector_type(2)))  float    floatx2;
typedef __attribute__((ext_vector_type(4)))  float    floatx4;
typedef __attribute__((ext_vector_type(4), aligned(4))) float floatx4u; // 4B-aligned 16B load
typedef __attribute__((ext_vector_type(2)))  __bf16   bf16x2;

__device__ inline unsigned pkbf(float a, float b) {   // v_cvt_pk_bf16_f32 (RNE)
    bf16x2 p; p.x = (__bf16)a; p.y = (__bf16)b;
    unsigned u; __builtin_memcpy(&u, &p, 4); return u;
}

// ---------- single fused kernel: one wave per atom ----------
// R3 body (packed h1/h2 + MFMA P + VALU A/D) with prep fused in:
// weights are preprocessed per block straight into LDS (overlaps with the
// block's L2 loads), and neighbor positions are gathered directly from pos
// via one dword-aligned dwordx4 per lane. No prep dispatch, no ws.
__global__ __launch_bounds__(256) void desc_kernel(
    const float* __restrict__ pos, const int* __restrict__ types,
    const int*   __restrict__ neigh,    // [S*N*M]
    const float* __restrict__ es1_w, const float* __restrict__ es1_b,
    const float* __restrict__ es2_w, const float* __restrict__ es2_b,
    const float* __restrict__ fs1_w, const float* __restrict__ fs1_b,
    const float* __restrict__ fs2_w, const float* __restrict__ fs2_b,
    const float* __restrict__ en1_w, const float* __restrict__ en1_b,
    const float* __restrict__ en2_w, const float* __restrict__ en2_b,
    const float* __restrict__ en3_w, const float* __restrict__ en3_b,
    float* __restrict__ out)            // [S*N*32*16]
{
    __shared__ alignas(16) unsigned short sh_h2[4][16][72]; // bf16 [wave][h][m]
    __shared__ alignas(16) unsigned short sh_rt[4][4][72];  // bf16 [wave][d][m]
    __shared__ alignas(16) float sh_PT[4][4][20];           // fp32 P^T [wave][d][h]
    __shared__ alignas(16) float sh_W3p[512];               // paired en3
    __shared__ alignas(16) float sh_b3p[16][2];
    __shared__ alignas(16) float sh_A[4][128];              // A[g][d] flat g*4+d
    __shared__ alignas(16) float sh_vt[4][8];

    const int tid = threadIdx.x;

    // ---- fused weight prep: per block, straight into LDS ----
    if (tid < 4) {  // species-pair table -> vt = td @ en1_w
        const float ti = (float)(tid >> 1), tj = (float)(tid & 1);
        float e[4] = {0.f, 0.f, 0.f, 0.f};
        #pragma unroll
        for (int swp = 0; swp < 2; ++swp) {
            const float a = swp ? tj : ti, bb = swp ? ti : tj;
            float h[4];
            #pragma unroll
            for (int k = 0; k < 4; ++k)
                h[k] = fmaxf(a * es1_w[k] + bb * es1_w[4 + k] + es1_b[k], 0.f);
            #pragma unroll
            for (int k = 0; k < 4; ++k) {
                float acc = es2_b[k];
                #pragma unroll
                for (int j = 0; j < 4; ++j) acc += h[j] * es2_w[j * 4 + k];
                e[k] += acc;
            }
        }
        float f[4];
        #pragma unroll
        for (int k = 0; k < 4; ++k) {
            float acc = fs1_b[k];
            #pragma unroll
            for (int j = 0; j < 4; ++j) acc += e[j] * fs1_w[j * 4 + k];
            f[k] = fmaxf(acc, 0.f);
        }
        float td[4];
        #pragma unroll
        for (int k = 0; k < 4; ++k) {
            float acc = fs2_b[k];
            #pragma unroll
            for (int j = 0; j < 4; ++j) acc += f[j] * fs2_w[j * 4 + k];
            td[k] = acc;
        }
        #pragma unroll
        for (int o = 0; o < 8; ++o) {
            float acc = 0.f;
            #pragma unroll
            for (int d = 0; d < 4; ++d) acc += td[d] * en1_w[d * 8 + o];
            sh_vt[tid][o] = acc;
        }
    }
    if (tid < 32)  // b3p: {b3[g], b3[g+16]} pairs
        ((float*)sh_b3p)[tid] = en3_b[(tid & 1) * 16 + (tid >> 1)];
    #pragma unroll
    for (int rr = 0; rr < 2; ++rr) {   // en3 paired for v_pk_fma A-step
        const int i = tid + rr * 256;
        const int hp = i >> 6, g = (i >> 2) & 15, w = i & 3;
        sh_W3p[i] = en3_w[(2 * hp + (w >> 1)) * 32 + g + 16 * (w & 1)];
    }
    __syncthreads();

    const int wave = __builtin_amdgcn_readfirstlane(tid >> 6);
    const int lane = tid & 63;
    const int atom = __builtin_amdgcn_readfirstlane(blockIdx.x * 4 + (tid >> 6));
    const int sbase = atom & ~(NN - 1);

    // ---- self atom: wave-uniform -> s_loads ----
    const float xi = pos[atom * 3 + 0];
    const float yi = pos[atom * 3 + 1];
    const float zi = pos[atom * 3 + 2];
    const int   ti = types[atom];

    // ---- neighbor gather: one dword-aligned dwordx4 + one dword ----
    const int nb  = neigh[atom * MM + lane];
    const int msk = nb < 0;
    const int ja  = sbase + (msk ? 0 : nb);
    const int ja3 = ja * 3;
    const int shft = (ja3 + 4 > SS * NN * 3);   // 16B read would run off the end
    const int ja3c = shft ? ja3 - 1 : ja3;
    floatx4u pv4;
    __builtin_memcpy(&pv4, pos + ja3c, 16);
    const float pjx = shft ? pv4.y : pv4.x;
    const float pjy = shft ? pv4.z : pv4.y;
    const float pjz = shft ? pv4.w : pv4.z;
    const int   tj  = types[ja];

    float dx = pjx - xi;
    float dy = pjy - yi;
    float dz = pjz - zi;
    dx -= LBOX * rintf(dx * (1.0f / LBOX));
    dy -= LBOX * rintf(dy * (1.0f / LBOX));
    dz -= LBOX * rintf(dz * (1.0f / LBOX));
    const float r2   = fmaf(dx, dx, fmaf(dy, dy, fmaf(dz, dz, 1e-12f)));
    const float rinv = rsqrtf(r2);
    const float r    = r2 * rinv;
    const float u    = fminf(fmaxf((r - 2.0f) * 0.25f, 0.0f), 1.0f);
    const float swv  = 0.5f * __cosf(3.14159265358979323846f * u) + 0.5f;
    const float sij   = msk ? 0.0f : swv * rinv;
    const float scale = sij * rinv;
    const int   tt    = ti * 2 + tj;

    // ---- h1 = relu(sij*vt[tt] + b1) on v_pk_fma_f32 pairs ----
    const floatx2 zero2 = {0.f, 0.f};
    const floatx2 sij2  = {sij, sij};
    float h1[8];
    #pragma unroll
    for (int j = 0; j < 4; ++j) {
        const floatx2 vtp = *(const floatx2*)&sh_vt[tt][j * 2];
        const floatx2 ebp = *(const floatx2*)&en1_b[j * 2];
        floatx2 hp = sij2 * vtp + ebp;
        hp = __builtin_elementwise_max(hp, zero2);
        h1[j * 2]     = hp.x;
        h1[j * 2 + 1] = hp.y;
    }

    // ---- h2 = relu(h1 @ W2 + b2), packed pairs -> bf16 LDS [h][m] ----
    {
        floatx2 acc[8];
        #pragma unroll
        for (int kp = 0; kp < 8; ++kp)
            acc[kp] = *(const floatx2*)&en2_b[kp * 2];
        #pragma unroll
        for (int i = 0; i < 8; ++i) {
            const floatx2 hi = {h1[i], h1[i]};
            #pragma unroll
            for (int kp = 0; kp < 8; ++kp)
                acc[kp] += hi * (*(const floatx2*)&en2_w[i * 16 + kp * 2]);
        }
        #pragma unroll
        for (int kp = 0; kp < 8; ++kp) {
            const floatx2 a = __builtin_elementwise_max(acc[kp], zero2);
            const unsigned pk = pkbf(a.x, a.y);
            sh_h2[wave][kp * 2][lane]     = (unsigned short)pk;
            sh_h2[wave][kp * 2 + 1][lane] = (unsigned short)(pk >> 16);
        }
    }
    {
        const unsigned p0 = pkbf(sij, dx * scale), p1 = pkbf(dy * scale, dz * scale);
        sh_rt[wave][0][lane] = (unsigned short)p0;
        sh_rt[wave][1][lane] = (unsigned short)(p0 >> 16);
        sh_rt[wave][2][lane] = (unsigned short)p1;
        sh_rt[wave][3][lane] = (unsigned short)(p1 >> 16);
    }
    asm volatile("s_waitcnt lgkmcnt(0)" ::: "memory");   // wave-private staging

    // ---- P = H2^T R and q = 1^T R on the matrix pipe ----
    const int col16 = lane & 15;
    const int q4    = lane >> 4;
    const int m0    = q4 * 8;
    floatx4 cP = {0.f, 0.f, 0.f, 0.f};
    floatx4 cQ = {0.f, 0.f, 0.f, 0.f};
    const short8 ones = (short8)(short)0x3F80;
    #pragma unroll
    for (int ck = 0; ck < 2; ++ck) {
        const short8 af = *(const short8*)&sh_h2[wave][col16][ck * 32 + m0];
        const short8 bf = *(const short8*)&sh_rt[wave][col16 & 3][ck * 32 + m0];
        cP = __builtin_amdgcn_mfma_f32_16x16x32_bf16(af, bf, cP, 0, 0, 0);
        cQ = __builtin_amdgcn_mfma_f32_16x16x32_bf16(ones, bf, cQ, 0, 0, 0);
    }
    if (col16 < 4) *(floatx4*)&sh_PT[wave][col16][q4 * 4] = cP;
    const float qd = cQ[0];                    // q[lane&3]
    asm volatile("s_waitcnt lgkmcnt(0)" ::: "memory");

    // ---- A[g][d] = en3^T P + b3 q  (v_pk_fma pairs g,g+16) ----
    {
        const int g0 = lane >> 2, dd = lane & 3;
        const floatx2 b3v = *(const floatx2*)&sh_b3p[g0][0];
        floatx2 acc2 = floatx2{qd, qd} * b3v;
        #pragma unroll
        for (int h4 = 0; h4 < 4; ++h4) {
            const floatx4 pv = *(const floatx4*)&sh_PT[wave][dd][h4 * 4];
            const floatx4 wa = *(const floatx4*)&sh_W3p[(h4 * 2 + 0) * 64 + g0 * 4];
            const floatx4 wb = *(const floatx4*)&sh_W3p[(h4 * 2 + 1) * 64 + g0 * 4];
            acc2 += floatx2{pv.x, pv.x} * floatx2{wa.x, wa.y};
            acc2 += floatx2{pv.y, pv.y} * floatx2{wa.z, wa.w};
            acc2 += floatx2{pv.z, pv.z} * floatx2{wb.x, wb.y};
            acc2 += floatx2{pv.w, pv.w} * floatx2{wb.z, wb.w};
        }
        sh_A[wave][lane]      = acc2.x;   // lane == g0*4+dd
        sh_A[wave][lane + 64] = acc2.y;
    }
    asm volatile("s_waitcnt lgkmcnt(0)" ::: "memory");

    // ---- D[g][k] = A A[:16]^T ; coalesced nt store ----
    {
        const int g = lane >> 1, koff = (lane & 1) * 8;
        const floatx4 Ag = *(const floatx4*)&sh_A[wave][g * 4];
        floatx4 o0, o1;
        #pragma unroll
        for (int jj = 0; jj < 8; ++jj) {
            const floatx4 Ak = *(const floatx4*)&sh_A[wave][(koff + jj) * 4];
            const float v = fmaf(Ag.x, Ak.x, fmaf(Ag.y, Ak.y, fmaf(Ag.z, Ak.z, Ag.w * Ak.w)));
            if (jj < 4) o0[jj] = v; else o1[jj - 4] = v;
        }
        float* op = out + (size_t)atom * 512 + lane * 8;
        __builtin_nontemporal_store(o0, (floatx4*)op);
        __builtin_nontemporal_store(o1, (floatx4*)(op + 4));
    }
}

extern "C" void kernel_launch(void* const* d_in, const int* in_sizes, int n_in,
                              void* d_out, int out_size, void* d_ws, size_t ws_size,
                              hipStream_t stream) {
    desc_kernel<<<dim3((SS * NN) / 4), dim3(256), 0, stream>>>(
        (const float*)d_in[0],  (const int*)d_in[1],  (const int*)d_in[2],
        (const float*)d_in[3],  (const float*)d_in[4],
        (const float*)d_in[5],  (const float*)d_in[6],
        (const float*)d_in[7],  (const float*)d_in[8],
        (const float*)d_in[9],  (const float*)d_in[10],
        (const float*)d_in[11], (const float*)d_in[12],
        (const float*)d_in[13], (const float*)d_in[14],
        (const float*)d_in[15], (const float*)d_in[16],
        (float*)d_out);
}

// Round 5
// 126.938 us; speedup vs baseline: 1.0255x; 1.0255x over previous
//
#include <hip/hip_runtime.h>
#include <math.h>

#define SS 8
#define NN 4096
#define MM 64
#define LBOX 20.0f

typedef __attribute__((ext_vector_type(8)))  short    short8;
typedef __attribute__((ext_vector_type(4)))  short    s16x4;
typedef __attribute__((ext_vector_type(2)))  float    floatx2;
typedef __attribute__((ext_vector_type(4)))  float    floatx4;
typedef __attribute__((ext_vector_type(2)))  unsigned uintx2;
typedef __attribute__((ext_vector_type(2)))  __bf16   bf16x2;

__device__ inline unsigned pkbf(float a, float b) {   // v_cvt_pk_bf16_f32 (RNE)
    bf16x2 p; p.x = (__bf16)a; p.y = (__bf16)b;
    unsigned u; __builtin_memcpy(&u, &p, 4); return u;
}

#if defined(__has_builtin)
#  if __has_builtin(__builtin_amdgcn_mfma_f32_16x16x16bf16_1k)
#    define MFMA16(a,b,c) __builtin_amdgcn_mfma_f32_16x16x16bf16_1k(a,b,c,0,0,0)
#  endif
#endif
#ifndef MFMA16
static __device__ inline floatx4 mfma16_asm(s16x4 a, s16x4 b, floatx4 c) {
    floatx4 d;
    asm("v_mfma_f32_16x16x16_bf16 %0, %1, %2, %3\n\ts_nop 7\n\ts_nop 7"
        : "=v"(d) : "v"(a), "v"(b), "v"(c));
    return d;
}
#  define MFMA16(a,b,c) mfma16_asm(a,b,c)
#endif

// d_ws layout: [0, 524288)      posw: float4 {x,y,z,bitcast(type)} per atom (S*N = 32768)
//              [524288, ...)    weights (fp32/bf16):
//                vt[32] | b3[32] | w3f: 2 halves x 64 lanes x 4 bf16 (A-frag layout)
#define WS_POSW   0
#define WS_WT     (524288 / 4)     // float offset
#define WT_VT     0
#define WT_B3     32
#define WT_W3F    64               // 128 x uintx2 (1024 B)

// ---------- prep kernel: runs every launch (ws is re-poisoned). ----------
// blocks 0..127: pack posw. block 128: preprocess weights.
__global__ __launch_bounds__(256) void prep_kernel(
    const float* __restrict__ pos, const int* __restrict__ types,
    const float* __restrict__ es1_w, const float* __restrict__ es1_b,
    const float* __restrict__ es2_w, const float* __restrict__ es2_b,
    const float* __restrict__ fs1_w, const float* __restrict__ fs1_b,
    const float* __restrict__ fs2_w, const float* __restrict__ fs2_b,
    const float* __restrict__ en1_w, const float* __restrict__ en3_w,
    const float* __restrict__ en3_b, float* __restrict__ ws)
{
    const int tid = threadIdx.x;
    const int b = blockIdx.x;
    if (b < 128) {
        const int i = b * 256 + tid;
        floatx4 v;
        v.x = pos[i * 3 + 0];
        v.y = pos[i * 3 + 1];
        v.z = pos[i * 3 + 2];
        v.w = __int_as_float(types[i]);
        *((floatx4*)ws + i) = v;
        return;
    }
    float* wt = ws + WS_WT;
    if (tid < 4) {  // species-pair table -> vt = td @ en1_w
        const float ti = (float)(tid >> 1), tj = (float)(tid & 1);
        float e[4] = {0.f, 0.f, 0.f, 0.f};
        #pragma unroll
        for (int swp = 0; swp < 2; ++swp) {
            const float a = swp ? tj : ti, bb = swp ? ti : tj;
            float h[4];
            #pragma unroll
            for (int k = 0; k < 4; ++k)
                h[k] = fmaxf(a * es1_w[k] + bb * es1_w[4 + k] + es1_b[k], 0.f);
            #pragma unroll
            for (int k = 0; k < 4; ++k) {
                float acc = es2_b[k];
                #pragma unroll
                for (int j = 0; j < 4; ++j) acc += h[j] * es2_w[j * 4 + k];
                e[k] += acc;
            }
        }
        float f[4];
        #pragma unroll
        for (int k = 0; k < 4; ++k) {
            float acc = fs1_b[k];
            #pragma unroll
            for (int j = 0; j < 4; ++j) acc += e[j] * fs1_w[j * 4 + k];
            f[k] = fmaxf(acc, 0.f);
        }
        float td[4];
        #pragma unroll
        for (int k = 0; k < 4; ++k) {
            float acc = fs2_b[k];
            #pragma unroll
            for (int j = 0; j < 4; ++j) acc += f[j] * fs2_w[j * 4 + k];
            td[k] = acc;
        }
        #pragma unroll
        for (int o = 0; o < 8; ++o) {
            float acc = 0.f;
            #pragma unroll
            for (int d = 0; d < 4; ++d) acc += td[d] * en1_w[d * 8 + o];
            wt[WT_VT + tid * 8 + o] = acc;
        }
    }
    if (tid < 32)   // plain en3 bias
        wt[WT_B3 + tid] = en3_b[tid];
    if (tid < 128) {  // en3_w -> bf16 MFMA A-fragment layout, per g-half
        const int half = tid >> 6, l = tid & 63;
        const int q4 = l >> 4, col = l & 15;
        const int gg = half * 16 + col;
        float v0 = en3_w[(q4 * 4 + 0) * 32 + gg];
        float v1 = en3_w[(q4 * 4 + 1) * 32 + gg];
        float v2 = en3_w[(q4 * 4 + 2) * 32 + gg];
        float v3 = en3_w[(q4 * 4 + 3) * 32 + gg];
        uintx2 pk; pk.x = pkbf(v0, v1); pk.y = pkbf(v2, v3);
        ((uintx2*)(wt + WT_W3F))[tid] = pk;
    }
}

// ---------- main kernel: one wave per atom ----------
// R2 body (best measured) with occupancy fix: __launch_bounds__(256,4) caps
// VGPR at 128 (>=4 waves/SIMD), and h2 is kp-outer/i-inner so only 16
// weight floats are live at a time (RA sinks s_loads instead of spilling).
__global__ __launch_bounds__(256, 4) void desc_kernel(
    const float* __restrict__ ws,       // posw + preprocessed weights
    const int*   __restrict__ neigh,    // [S*N*M]
    const float* __restrict__ en1_b,
    const float* __restrict__ en2_w, const float* __restrict__ en2_b,
    float* __restrict__ out)            // [S*N*32*16]
{
    __shared__ alignas(16) unsigned short sh_h2[4][16][72]; // bf16 [wave][h][m]
    __shared__ alignas(16) unsigned short sh_rt[4][4][72];  // bf16 [wave][d][m]
    __shared__ alignas(16) float sh_vt[4][8];
    __shared__ alignas(16) float sh_b3[32];
    __shared__ alignas(16) unsigned sh_w3f[2][64][2];       // bf16 A-frags of en3_w
    __shared__ alignas(16) unsigned short sh_Ab[4][32][4];  // bf16 A[g][d] per wave

    const int tid = threadIdx.x;
    const float* wt = ws + WS_WT;

    // ---- prologue: pure coalesced staging, no compute ----
    if (tid < 32) {
        ((float*)sh_vt)[tid] = wt[WT_VT + tid];
        sh_b3[tid]           = wt[WT_B3 + tid];
    }
    if (tid < 128)
        ((uintx2*)sh_w3f)[tid] = ((const uintx2*)(wt + WT_W3F))[tid];
    __syncthreads();

    const int wave = __builtin_amdgcn_readfirstlane(tid >> 6);
    const int lane = tid & 63;
    const int atom = __builtin_amdgcn_readfirstlane(blockIdx.x * 4 + (tid >> 6));
    const int sbase = atom & ~(NN - 1);
    const floatx4* __restrict__ pw = (const floatx4*)ws;

    // ---- gather: one dwordx4 per lane (pos+type packed) ----
    const floatx4 pi4 = pw[atom];                 // wave-uniform -> s_load
    const float xi = pi4.x, yi = pi4.y, zi = pi4.z;
    const int   ti = __float_as_int(pi4.w);

    const int nb  = neigh[atom * MM + lane];
    const int msk = nb < 0;
    const int gj  = sbase + (msk ? 0 : nb);
    const floatx4 pj4 = pw[gj];
    const int tj = __float_as_int(pj4.w);

    float dx = pj4.x - xi;
    float dy = pj4.y - yi;
    float dz = pj4.z - zi;
    dx -= LBOX * rintf(dx * (1.0f / LBOX));
    dy -= LBOX * rintf(dy * (1.0f / LBOX));
    dz -= LBOX * rintf(dz * (1.0f / LBOX));
    const float r2   = fmaf(dx, dx, fmaf(dy, dy, fmaf(dz, dz, 1e-12f)));
    const float rinv = rsqrtf(r2);
    const float r    = r2 * rinv;
    const float u    = fminf(fmaxf((r - 2.0f) * 0.25f, 0.0f), 1.0f);
    const float swv  = 0.5f * __cosf(3.14159265358979323846f * u) + 0.5f;
    const float sij   = msk ? 0.0f : swv * rinv;
    const float scale = sij * rinv;
    const int   tt    = ti * 2 + tj;

    // ---- h1 = relu(sij*vt[tt] + b1) on v_pk_fma_f32 pairs ----
    const floatx2 zero2 = {0.f, 0.f};
    const floatx2 sij2  = {sij, sij};
    float h1[8];
    #pragma unroll
    for (int j = 0; j < 4; ++j) {
        const floatx2 vtp = *(const floatx2*)&sh_vt[tt][j * 2];
        const floatx2 ebp = *(const floatx2*)&en1_b[j * 2];
        floatx2 hp = sij2 * vtp + ebp;
        hp = __builtin_elementwise_max(hp, zero2);
        h1[j * 2]     = hp.x;
        h1[j * 2 + 1] = hp.y;
    }

    // ---- h2 = relu(h1 @ W2 + b2), kp-outer: 16 live weight floats max ----
    {
        #pragma unroll
        for (int kp = 0; kp < 8; ++kp) {
            floatx2 acc = *(const floatx2*)&en2_b[kp * 2];
            #pragma unroll
            for (int i = 0; i < 8; ++i) {
                const floatx2 hi = {h1[i], h1[i]};
                acc += hi * (*(const floatx2*)&en2_w[i * 16 + kp * 2]);
            }
            const floatx2 a = __builtin_elementwise_max(acc, zero2);
            const unsigned pk = pkbf(a.x, a.y);
            sh_h2[wave][kp * 2][lane]     = (unsigned short)pk;
            sh_h2[wave][kp * 2 + 1][lane] = (unsigned short)(pk >> 16);
        }
    }
    {
        const unsigned p0 = pkbf(sij, dx * scale), p1 = pkbf(dy * scale, dz * scale);
        sh_rt[wave][0][lane] = (unsigned short)p0;
        sh_rt[wave][1][lane] = (unsigned short)(p0 >> 16);
        sh_rt[wave][2][lane] = (unsigned short)p1;
        sh_rt[wave][3][lane] = (unsigned short)(p1 >> 16);
    }
    asm volatile("s_waitcnt lgkmcnt(0)" ::: "memory");   // wave-private staging

    // ---- P = H2^T R and q = 1^T R on the matrix pipe ----
    const int col16 = lane & 15;
    const int q4    = lane >> 4;
    const int m0    = q4 * 8;
    floatx4 cP = {0.f, 0.f, 0.f, 0.f};
    floatx4 cQ = {0.f, 0.f, 0.f, 0.f};
    const short8 ones = (short8)(short)0x3F80;
    #pragma unroll
    for (int ck = 0; ck < 2; ++ck) {
        const short8 af = *(const short8*)&sh_h2[wave][col16][ck * 32 + m0];
        const short8 bf = *(const short8*)&sh_rt[wave][col16 & 3][ck * 32 + m0];
        cP = __builtin_amdgcn_mfma_f32_16x16x32_bf16(af, bf, cP, 0, 0, 0);
        cQ = __builtin_amdgcn_mfma_f32_16x16x32_bf16(ones, bf, cQ, 0, 0, 0);
    }
    // cP[j] = P[4*q4+j][col16&3] (d replicated over col16>>2)
    // cQ[j] = q[col16&3]

    // ---- A = W3^T P + b3 q via 2 MFMAs; cP already in B-frag layout ----
    s16x4 pfrag;
    {
        const unsigned p0 = pkbf(cP[0], cP[1]), p1 = pkbf(cP[2], cP[3]);
        unsigned* pp = (unsigned*)&pfrag; pp[0] = p0; pp[1] = p1;
    }
    const float qd = cQ[0];
    const s16x4 w3f0 = *(const s16x4*)&sh_w3f[0][lane][0];
    const s16x4 w3f1 = *(const s16x4*)&sh_w3f[1][lane][0];
    const floatx4 b3v0 = *(const floatx4*)&sh_b3[q4 * 4];
    const floatx4 b3v1 = *(const floatx4*)&sh_b3[16 + q4 * 4];
    const floatx4 cA0 = MFMA16(w3f0, pfrag, b3v0 * qd);   // A[4q4+j][col16&3], g<16
    const floatx4 cA1 = MFMA16(w3f1, pfrag, b3v1 * qd);   // g>=16

    // ---- D = A A16^T via 2 MFMAs (K=4 zero-padded to 16) ----
    if (col16 < 4) {   // 16 writer lanes per wave hold the full A (d = col16)
        #pragma unroll
        for (int j = 0; j < 4; ++j) {
            sh_Ab[wave][q4 * 4 + j][col16]      = (unsigned short)pkbf(cA0[j], 0.f);
            sh_Ab[wave][16 + q4 * 4 + j][col16] = (unsigned short)pkbf(cA1[j], 0.f);
        }
    }
    asm volatile("s_waitcnt lgkmcnt(0)" ::: "memory");   // wave-private staging
    s16x4 fA0 = *(const s16x4*)&sh_Ab[wave][col16][0];      // A[col16][0..3]
    s16x4 fA1 = *(const s16x4*)&sh_Ab[wave][16 + col16][0]; // A[16+col16][0..3]
    if (q4 != 0) { fA0 = (s16x4)(short)0; fA1 = (s16x4)(short)0; }  // zero K>=4 pad
    const floatx4 zz = {0.f, 0.f, 0.f, 0.f};
    const floatx4 cD0 = MFMA16(fA0, fA0, zz);   // D[4q4+j][col16], g<16 (fA0 doubles as A16^T B-frag)
    const floatx4 cD1 = MFMA16(fA1, fA0, zz);   // D[16+4q4+j][col16]

    // ---- store straight from C-layout: 8 nt dword stores, 64B-coalesced per 16 lanes ----
    float* op = out + (size_t)atom * 512;
    #pragma unroll
    for (int j = 0; j < 4; ++j) {
        __builtin_nontemporal_store(cD0[j], op + (q4 * 4 + j) * 16 + col16);
        __builtin_nontemporal_store(cD1[j], op + (16 + q4 * 4 + j) * 16 + col16);
    }
}

extern "C" void kernel_launch(void* const* d_in, const int* in_sizes, int n_in,
                              void* d_out, int out_size, void* d_ws, size_t ws_size,
                              hipStream_t stream) {
    const float* pos   = (const float*)d_in[0];
    const int*   typ   = (const int*)d_in[1];
    const int*   ngh   = (const int*)d_in[2];
    float* ws = (float*)d_ws;

    prep_kernel<<<dim3(129), dim3(256), 0, stream>>>(
        pos, typ,
        (const float*)d_in[3],  (const float*)d_in[4],
        (const float*)d_in[5],  (const float*)d_in[6],
        (const float*)d_in[7],  (const float*)d_in[8],
        (const float*)d_in[9],  (const float*)d_in[10],
        (const float*)d_in[11],                 // en1_w
        (const float*)d_in[15], (const float*)d_in[16],  // en3_w, en3_b
        ws);

    desc_kernel<<<dim3((SS * NN) / 4), dim3(256), 0, stream>>>(
        ws, ngh,
        (const float*)d_in[12],                 // en1_b
        (const float*)d_in[13], (const float*)d_in[14],  // en2_w, en2_b
        (float*)d_out);
}

// Round 6
// 124.634 us; speedup vs baseline: 1.0444x; 1.0185x over previous
//
#include <hip/hip_runtime.h>
#include <math.h>

#define SS 8
#define NN 4096
#define MM 64
#define LBOX 20.0f

typedef __attribute__((ext_vector_type(8)))  short    short8;
typedef __attribute__((ext_vector_type(4)))  short    s16x4;
typedef __attribute__((ext_vector_type(2)))  float    floatx2;
typedef __attribute__((ext_vector_type(4)))  float    floatx4;
typedef __attribute__((ext_vector_type(2)))  unsigned uintx2;
typedef __attribute__((ext_vector_type(2)))  __bf16   bf16x2;

__device__ inline unsigned pkbf(float a, float b) {   // v_cvt_pk_bf16_f32 (RNE)
    bf16x2 p; p.x = (__bf16)a; p.y = (__bf16)b;
    unsigned u; __builtin_memcpy(&u, &p, 4); return u;
}

#if defined(__has_builtin)
#  if __has_builtin(__builtin_amdgcn_mfma_f32_16x16x16bf16_1k)
#    define MFMA16(a,b,c) __builtin_amdgcn_mfma_f32_16x16x16bf16_1k(a,b,c,0,0,0)
#  endif
#endif
#ifndef MFMA16
static __device__ inline floatx4 mfma16_asm(s16x4 a, s16x4 b, floatx4 c) {
    floatx4 d;
    asm("v_mfma_f32_16x16x16_bf16 %0, %1, %2, %3\n\ts_nop 7\n\ts_nop 7"
        : "=v"(d) : "v"(a), "v"(b), "v"(c));
    return d;
}
#  define MFMA16(a,b,c) mfma16_asm(a,b,c)
#endif

// d_ws layout: [0, 524288)      posw: float4 {x,y,z,bitcast(type)} per atom (S*N = 32768)
//              [524288, ...)    weights (fp32/bf16):
//                vt[32] | b3[32] | w3f: 2 halves x 64 lanes x 4 bf16 (A-frag layout)
#define WS_POSW   0
#define WS_WT     (524288 / 4)     // float offset
#define WT_VT     0
#define WT_B3     32
#define WT_W3F    64               // 128 x uintx2 (1024 B)

// ---------- prep kernel: runs every launch (ws is re-poisoned). ----------
// blocks 0..127: pack posw. block 128: preprocess weights.
__global__ __launch_bounds__(256) void prep_kernel(
    const float* __restrict__ pos, const int* __restrict__ types,
    const float* __restrict__ es1_w, const float* __restrict__ es1_b,
    const float* __restrict__ es2_w, const float* __restrict__ es2_b,
    const float* __restrict__ fs1_w, const float* __restrict__ fs1_b,
    const float* __restrict__ fs2_w, const float* __restrict__ fs2_b,
    const float* __restrict__ en1_w, const float* __restrict__ en3_w,
    const float* __restrict__ en3_b, float* __restrict__ ws)
{
    const int tid = threadIdx.x;
    const int b = blockIdx.x;
    if (b < 128) {
        const int i = b * 256 + tid;
        floatx4 v;
        v.x = pos[i * 3 + 0];
        v.y = pos[i * 3 + 1];
        v.z = pos[i * 3 + 2];
        v.w = __int_as_float(types[i]);
        *((floatx4*)ws + i) = v;
        return;
    }
    float* wt = ws + WS_WT;
    if (tid < 4) {  // species-pair table -> vt = td @ en1_w
        const float ti = (float)(tid >> 1), tj = (float)(tid & 1);
        float e[4] = {0.f, 0.f, 0.f, 0.f};
        #pragma unroll
        for (int swp = 0; swp < 2; ++swp) {
            const float a = swp ? tj : ti, bb = swp ? ti : tj;
            float h[4];
            #pragma unroll
            for (int k = 0; k < 4; ++k)
                h[k] = fmaxf(a * es1_w[k] + bb * es1_w[4 + k] + es1_b[k], 0.f);
            #pragma unroll
            for (int k = 0; k < 4; ++k) {
                float acc = es2_b[k];
                #pragma unroll
                for (int j = 0; j < 4; ++j) acc += h[j] * es2_w[j * 4 + k];
                e[k] += acc;
            }
        }
        float f[4];
        #pragma unroll
        for (int k = 0; k < 4; ++k) {
            float acc = fs1_b[k];
            #pragma unroll
            for (int j = 0; j < 4; ++j) acc += e[j] * fs1_w[j * 4 + k];
            f[k] = fmaxf(acc, 0.f);
        }
        float td[4];
        #pragma unroll
        for (int k = 0; k < 4; ++k) {
            float acc = fs2_b[k];
            #pragma unroll
            for (int j = 0; j < 4; ++j) acc += f[j] * fs2_w[j * 4 + k];
            td[k] = acc;
        }
        #pragma unroll
        for (int o = 0; o < 8; ++o) {
            float acc = 0.f;
            #pragma unroll
            for (int d = 0; d < 4; ++d) acc += td[d] * en1_w[d * 8 + o];
            wt[WT_VT + tid * 8 + o] = acc;
        }
    }
    if (tid < 32)   // plain en3 bias
        wt[WT_B3 + tid] = en3_b[tid];
    if (tid < 128) {  // en3_w -> bf16 MFMA A-fragment layout, per g-half
        const int half = tid >> 6, l = tid & 63;
        const int q4 = l >> 4, col = l & 15;
        const int gg = half * 16 + col;
        float v0 = en3_w[(q4 * 4 + 0) * 32 + gg];
        float v1 = en3_w[(q4 * 4 + 1) * 32 + gg];
        float v2 = en3_w[(q4 * 4 + 2) * 32 + gg];
        float v3 = en3_w[(q4 * 4 + 3) * 32 + gg];
        uintx2 pk; pk.x = pkbf(v0, v1); pk.y = pkbf(v2, v3);
        ((uintx2*)(wt + WT_W3F))[tid] = pk;
    }
}

// ---------- main kernel: 4 atoms per wave, software-pipelined ----------
// 2048 blocks x 4 waves = 8192 waves = one residency generation. Each wave
// processes 4 atoms (stride 8192): all 4 neigh loads issued up-front, the
// dependent pos-gather for atom it+1 issued before computing atom it —
// independent work covers the load chain instead of lockstep generational
// stalls. Per-atom math identical to R2 (best measured).
__global__ __launch_bounds__(256) void desc_kernel(
    const float* __restrict__ ws,       // posw + preprocessed weights
    const int*   __restrict__ neigh,    // [S*N*M]
    const float* __restrict__ en1_b,
    const float* __restrict__ en2_w, const float* __restrict__ en2_b,
    float* __restrict__ out)            // [S*N*32*16]
{
    __shared__ alignas(16) unsigned short sh_h2[4][16][72]; // bf16 [wave][h][m]
    __shared__ alignas(16) unsigned short sh_rt[4][4][72];  // bf16 [wave][d][m]
    __shared__ alignas(16) float sh_vt[4][8];
    __shared__ alignas(16) float sh_b3[32];
    __shared__ alignas(16) unsigned sh_w3f[2][64][2];       // bf16 A-frags of en3_w
    __shared__ alignas(16) unsigned short sh_Ab[4][32][4];  // bf16 A[g][d] per wave

    const int tid = threadIdx.x;
    const float* wt = ws + WS_WT;

    // ---- prologue: pure coalesced staging, no compute ----
    if (tid < 32) {
        ((float*)sh_vt)[tid] = wt[WT_VT + tid];
        sh_b3[tid]           = wt[WT_B3 + tid];
    }
    if (tid < 128)
        ((uintx2*)sh_w3f)[tid] = ((const uintx2*)(wt + WT_W3F))[tid];
    __syncthreads();

    const int wave = __builtin_amdgcn_readfirstlane(tid >> 6);
    const int lane = tid & 63;
    const int a0   = __builtin_amdgcn_readfirstlane(blockIdx.x * 4 + (tid >> 6));
    const int sb0  = a0 & ~(NN - 1);
    const floatx4* __restrict__ pw = (const floatx4*)ws;

    const int col16 = lane & 15;
    const int q4    = lane >> 4;
    const int m0    = q4 * 8;
    const short8 ones = (short8)(short)0x3F80;
    const floatx2 zero2 = {0.f, 0.f};

    // ---- issue all 4 neigh loads up-front (independent, coalesced) ----
    int nbv[4];
    #pragma unroll
    for (int it = 0; it < 4; ++it)
        nbv[it] = neigh[(a0 + it * 8192) * MM + lane];

    // ---- first dependent gather ----
    floatx4 pj_cur;
    {
        const int nb = nbv[0];
        pj_cur = pw[sb0 + (nb < 0 ? 0 : nb)];
    }

    #pragma unroll
    for (int it = 0; it < 4; ++it) {
        const int atom  = a0 + it * 8192;           // wave-uniform
        const int msk   = nbv[it] < 0;
        const floatx4 pj4 = pj_cur;
        if (it < 3) {   // prefetch next gather under this iteration's compute
            const int nbn = nbv[it + 1];
            pj_cur = pw[sb0 + (it + 1) * 8192 + (nbn < 0 ? 0 : nbn)];
        }
        const floatx4 pi4 = pw[atom];               // uniform -> s_load
        const float xi = pi4.x, yi = pi4.y, zi = pi4.z;
        const int   ti = __float_as_int(pi4.w);
        const int   tj = __float_as_int(pj4.w);

        float dx = pj4.x - xi;
        float dy = pj4.y - yi;
        float dz = pj4.z - zi;
        dx -= LBOX * rintf(dx * (1.0f / LBOX));
        dy -= LBOX * rintf(dy * (1.0f / LBOX));
        dz -= LBOX * rintf(dz * (1.0f / LBOX));
        const float r2   = fmaf(dx, dx, fmaf(dy, dy, fmaf(dz, dz, 1e-12f)));
        const float rinv = rsqrtf(r2);
        const float r    = r2 * rinv;
        const float u    = fminf(fmaxf((r - 2.0f) * 0.25f, 0.0f), 1.0f);
        const float swv  = 0.5f * __cosf(3.14159265358979323846f * u) + 0.5f;
        const float sij   = msk ? 0.0f : swv * rinv;
        const float scale = sij * rinv;
        const int   tt    = ti * 2 + tj;

        // ---- h1 = relu(sij*vt[tt] + b1) on v_pk_fma_f32 pairs ----
        const floatx2 sij2 = {sij, sij};
        float h1[8];
        #pragma unroll
        for (int j = 0; j < 4; ++j) {
            const floatx2 vtp = *(const floatx2*)&sh_vt[tt][j * 2];
            const floatx2 ebp = *(const floatx2*)&en1_b[j * 2];
            floatx2 hp = sij2 * vtp + ebp;
            hp = __builtin_elementwise_max(hp, zero2);
            h1[j * 2]     = hp.x;
            h1[j * 2 + 1] = hp.y;
        }

        // ---- h2 = relu(h1 @ W2 + b2), packed pairs -> bf16 LDS [h][m] ----
        {
            floatx2 acc[8];
            #pragma unroll
            for (int kp = 0; kp < 8; ++kp)
                acc[kp] = *(const floatx2*)&en2_b[kp * 2];
            #pragma unroll
            for (int i = 0; i < 8; ++i) {
                const floatx2 hi = {h1[i], h1[i]};
                #pragma unroll
                for (int kp = 0; kp < 8; ++kp)
                    acc[kp] += hi * (*(const floatx2*)&en2_w[i * 16 + kp * 2]);
            }
            #pragma unroll
            for (int kp = 0; kp < 8; ++kp) {
                const floatx2 a = __builtin_elementwise_max(acc[kp], zero2);
                const unsigned pk = pkbf(a.x, a.y);
                sh_h2[wave][kp * 2][lane]     = (unsigned short)pk;
                sh_h2[wave][kp * 2 + 1][lane] = (unsigned short)(pk >> 16);
            }
        }
        {
            const unsigned p0 = pkbf(sij, dx * scale), p1 = pkbf(dy * scale, dz * scale);
            sh_rt[wave][0][lane] = (unsigned short)p0;
            sh_rt[wave][1][lane] = (unsigned short)(p0 >> 16);
            sh_rt[wave][2][lane] = (unsigned short)p1;
            sh_rt[wave][3][lane] = (unsigned short)(p1 >> 16);
        }
        asm volatile("s_waitcnt lgkmcnt(0)" ::: "memory");   // wave-private staging

        // ---- P = H2^T R and q = 1^T R on the matrix pipe ----
        floatx4 cP = {0.f, 0.f, 0.f, 0.f};
        floatx4 cQ = {0.f, 0.f, 0.f, 0.f};
        #pragma unroll
        for (int ck = 0; ck < 2; ++ck) {
            const short8 af = *(const short8*)&sh_h2[wave][col16][ck * 32 + m0];
            const short8 bf = *(const short8*)&sh_rt[wave][col16 & 3][ck * 32 + m0];
            cP = __builtin_amdgcn_mfma_f32_16x16x32_bf16(af, bf, cP, 0, 0, 0);
            cQ = __builtin_amdgcn_mfma_f32_16x16x32_bf16(ones, bf, cQ, 0, 0, 0);
        }
        // cP[j] = P[4*q4+j][col16&3] (d replicated over col16>>2); cQ[j] = q[col16&3]

        // ---- A = W3^T P + b3 q via 2 MFMAs; cP already in B-frag layout ----
        s16x4 pfrag;
        {
            const unsigned p0 = pkbf(cP[0], cP[1]), p1 = pkbf(cP[2], cP[3]);
            unsigned* pp = (unsigned*)&pfrag; pp[0] = p0; pp[1] = p1;
        }
        const float qd = cQ[0];
        const s16x4 w3f0 = *(const s16x4*)&sh_w3f[0][lane][0];
        const s16x4 w3f1 = *(const s16x4*)&sh_w3f[1][lane][0];
        const floatx4 b3v0 = *(const floatx4*)&sh_b3[q4 * 4];
        const floatx4 b3v1 = *(const floatx4*)&sh_b3[16 + q4 * 4];
        const floatx4 cA0 = MFMA16(w3f0, pfrag, b3v0 * qd);   // A[4q4+j][col16&3], g<16
        const floatx4 cA1 = MFMA16(w3f1, pfrag, b3v1 * qd);   // g>=16

        // ---- D = A A16^T via 2 MFMAs (K=4 zero-padded to 16) ----
        if (col16 < 4) {   // 16 writer lanes per wave hold the full A (d = col16)
            #pragma unroll
            for (int j = 0; j < 4; ++j) {
                sh_Ab[wave][q4 * 4 + j][col16]      = (unsigned short)pkbf(cA0[j], 0.f);
                sh_Ab[wave][16 + q4 * 4 + j][col16] = (unsigned short)pkbf(cA1[j], 0.f);
            }
        }
        asm volatile("s_waitcnt lgkmcnt(0)" ::: "memory");   // wave-private staging
        s16x4 fA0 = *(const s16x4*)&sh_Ab[wave][col16][0];      // A[col16][0..3]
        s16x4 fA1 = *(const s16x4*)&sh_Ab[wave][16 + col16][0]; // A[16+col16][0..3]
        if (q4 != 0) { fA0 = (s16x4)(short)0; fA1 = (s16x4)(short)0; }  // zero K>=4 pad
        const floatx4 zz = {0.f, 0.f, 0.f, 0.f};
        const floatx4 cD0 = MFMA16(fA0, fA0, zz);   // D[4q4+j][col16] (fA0 doubles as B-frag)
        const floatx4 cD1 = MFMA16(fA1, fA0, zz);   // D[16+4q4+j][col16]

        // ---- store straight from C-layout: 8 nt dword stores ----
        float* op = out + (size_t)atom * 512;
        #pragma unroll
        for (int j = 0; j < 4; ++j) {
            __builtin_nontemporal_store(cD0[j], op + (q4 * 4 + j) * 16 + col16);
            __builtin_nontemporal_store(cD1[j], op + (16 + q4 * 4 + j) * 16 + col16);
        }
        asm volatile("s_waitcnt lgkmcnt(0)" ::: "memory");   // keep iterations' LDS ordered
    }
}

extern "C" void kernel_launch(void* const* d_in, const int* in_sizes, int n_in,
                              void* d_out, int out_size, void* d_ws, size_t ws_size,
                              hipStream_t stream) {
    const float* pos   = (const float*)d_in[0];
    const int*   typ   = (const int*)d_in[1];
    const int*   ngh   = (const int*)d_in[2];
    float* ws = (float*)d_ws;

    prep_kernel<<<dim3(129), dim3(256), 0, stream>>>(
        pos, typ,
        (const float*)d_in[3],  (const float*)d_in[4],
        (const float*)d_in[5],  (const float*)d_in[6],
        (const float*)d_in[7],  (const float*)d_in[8],
        (const float*)d_in[9],  (const float*)d_in[10],
        (const float*)d_in[11],                 // en1_w
        (const float*)d_in[15], (const float*)d_in[16],  // en3_w, en3_b
        ws);

    desc_kernel<<<dim3((SS * NN) / 16), dim3(256), 0, stream>>>(
        ws, ngh,
        (const float*)d_in[12],                 // en1_b
        (const float*)d_in[13], (const float*)d_in[14],  // en2_w, en2_b
        (float*)d_out);
}